// Round 10
// baseline (150.005 us; speedup 1.0000x reference)
//
#include <hip/hip_runtime.h>
#include <hip/hip_bf16.h>

#define BATCH 64
#define MDIM 512
#define NDIM 1024
#define KDIM 1024

#define BM 256
#define BN 256
#define BK 64
#define NKT (KDIM / BK)     // 16 K-tiles

typedef __attribute__((ext_vector_type(4))) float f32x4;
typedef __attribute__((ext_vector_type(8))) short bf16x8;
typedef __attribute__((ext_vector_type(4))) unsigned int u32x4;

// fp32 pair -> packed bf16x2 (RNE); emits v_cvt_pk_bf16_f32
__device__ __forceinline__ unsigned int cvt2(float lo, float hi) {
    __hip_bfloat162 h = __float22bfloat162_rn(float2{lo, hi});
    return *(unsigned int*)&h;
}

#define MFMA16(a, b, c) __builtin_amdgcn_mfma_f32_16x16x32_bf16((a), (b), (c), 0, 0, 0)

// One seal per K-tile: drain OUR ds ops (CVTW writes published; any residual
// reads returned), raw s_barrier, and a sched fence so next-tile ds_reads
// can't hoist above the barrier (rule 18). NO vmcnt drain anywhere — global
// staging loads stay in flight across the barrier (T4).
#define TILE_SEAL do { \
    asm volatile("s_waitcnt lgkmcnt(0)" ::: "memory"); \
    __builtin_amdgcn_sched_barrier(0); \
    __builtin_amdgcn_s_barrier(); \
    __builtin_amdgcn_sched_barrier(0); } while (0)

__global__ __launch_bounds__(512, 2)
void grouped_fc_kernel(const float* __restrict__ X,
                       const float* __restrict__ W,
                       const float* __restrict__ Bias,
                       float* __restrict__ Out) {
    // XCD swizzle (bijective: 512 % 8 == 0): XCD j gets batches [8j, 8j+8)
    const int swz  = (blockIdx.x & 7) * 64 + (blockIdx.x >> 3);
    const int bidx = swz >> 3;     // 0..63 batch
    const int tile = swz & 7;      // 2 M-tiles x 4 N-tiles
    const int tm = tile & 1;
    const int tn = tile >> 1;

    const int tid  = threadIdx.x;
    const int lane = tid & 63;
    const int wid  = tid >> 6;     // 0..7
    const int wm   = wid & 1;      // 2 wave rows (128 out-rows)
    const int wn   = wid >> 1;     // 4 wave cols (64 out-cols)

    // [row][64] bf16 = 8 x 16B slots/row; slot s stored at s ^ (row&7).
    // R9-verified: SQ_LDS_BANK_CONFLICT == 0 (reads and writes both uniform
    // 8 lanes per 16B granule). 128 KiB total.
    __shared__ unsigned short ldsA[2][BM][BK];
    __shared__ unsigned short ldsB[2][BN][BK];

    const float* srcA = X + ((size_t)bidx * MDIM + (size_t)tm * BM) * KDIM;
    const float* srcB = W + ((size_t)bidx * NDIM + (size_t)tn * BN) * KDIM;

    // staging: 4 threads per row; thread covers 16 fp32 (2 bf16 slots) of a
    // 128-row half-tile
    const int s_r  = tid >> 2;             // 0..127 row within half
    const int s_cf = (tid & 3) * 16;       // fp32 col offset
    const int s_x  = s_r & 7;              // (hv*128)&7 == 0
    const int so0  = (((tid & 3) * 2)     ^ s_x) * 8;  // swizzled elem offs
    const int so1  = (((tid & 3) * 2 + 1) ^ s_x) * 8;

    f32x4 st0[4], st1[4];                  // ping-pong staging sets (A then B)

    auto ISSUE = [&](const float* srcbase, int hv, int kt_, f32x4 (&s)[4]) {
        const float* p = srcbase + (size_t)(hv * 128 + s_r) * KDIM + kt_ * BK + s_cf;
#pragma unroll
        for (int v = 0; v < 4; ++v) s[v] = *(const f32x4*)(p + v * 4);
    };

    auto CVTW = [&](unsigned short* ldsbase, int hv, f32x4 (&s)[4]) {
        const int row = hv * 128 + s_r;
        u32x4 w0, w1;
        w0[0] = cvt2(s[0][0], s[0][1]); w0[1] = cvt2(s[0][2], s[0][3]);
        w0[2] = cvt2(s[1][0], s[1][1]); w0[3] = cvt2(s[1][2], s[1][3]);
        w1[0] = cvt2(s[2][0], s[2][1]); w1[1] = cvt2(s[2][2], s[2][3]);
        w1[2] = cvt2(s[3][0], s[3][1]); w1[3] = cvt2(s[3][2], s[3][3]);
        *(u32x4*)&ldsbase[(size_t)row * BK + so0] = w0;
        *(u32x4*)&ldsbase[(size_t)row * BK + so1] = w1;
    };

    // frag read offsets: row&7 == frow&7 (frag base rows are multiples of 8)
    const int frow = lane & 15;
    const int khi  = lane >> 4;            // k sub-slot 0..3
    const int xr   = frow & 7;
    const int oK0  = ((khi)     ^ xr) * 8; // ks=0: slot khi
    const int oK1  = ((4 + khi) ^ xr) * 8; // ks=1: slot 4+khi

    f32x4 acc[8][4];
#pragma unroll
    for (int mi = 0; mi < 8; ++mi)
#pragma unroll
        for (int ni = 0; ni < 4; ++ni)
            acc[mi][ni] = (f32x4){0.f, 0.f, 0.f, 0.f};

    // ---- prologue: stage tile 0 -> buf0 ----
    ISSUE(srcA, 0, 0, st0); ISSUE(srcA, 1, 0, st1);
    CVTW(&ldsA[0][0][0], 0, st0); CVTW(&ldsA[0][0][0], 1, st1);
    ISSUE(srcB, 0, 0, st0); ISSUE(srcB, 1, 0, st1);
    CVTW(&ldsB[0][0][0], 0, st0); CVTW(&ldsB[0][0][0], 1, st1);
    TILE_SEAL;

#pragma unroll 1
    for (int kt = 0; kt < NKT; ++kt) {
        const int rd = kt & 1;
        const bool m1 = (kt + 1 < NKT);
        unsigned short* nA = &ldsA[rd ^ 1][0][0];
        unsigned short* nB = &ldsB[rd ^ 1][0][0];
        bf16x8 af[8], bfr[4];

        // issue A(t+1) early — lands during MFMA-ks0
        if (m1) { ISSUE(srcA, 0, kt + 1, st0); ISSUE(srcA, 1, kt + 1, st1); }

        // reads ks0 (compiler interleaves fine-grained lgkmcnt with MFMAs)
#pragma unroll
        for (int mi = 0; mi < 8; ++mi)
            af[mi] = *(const bf16x8*)&ldsA[rd][wm * 128 + mi * 16 + frow][oK0];
#pragma unroll
        for (int ni = 0; ni < 4; ++ni)
            bfr[ni] = *(const bf16x8*)&ldsB[rd][wn * 64 + ni * 16 + frow][oK0];

        __builtin_amdgcn_s_setprio(1);
#pragma unroll
        for (int mi = 0; mi < 8; ++mi)
#pragma unroll
            for (int ni = 0; ni < 4; ++ni)
                acc[mi][ni] = MFMA16(af[mi], bfr[ni], acc[mi][ni]);
        __builtin_amdgcn_s_setprio(0);

        // publish A(t+1), then reuse staging regs for B(t+1)
        if (m1) {
            CVTW(nA, 0, st0); CVTW(nA, 1, st1);
            ISSUE(srcB, 0, kt + 1, st0); ISSUE(srcB, 1, kt + 1, st1);
        }

        // reads ks1
#pragma unroll
        for (int mi = 0; mi < 8; ++mi)
            af[mi] = *(const bf16x8*)&ldsA[rd][wm * 128 + mi * 16 + frow][oK1];
#pragma unroll
        for (int ni = 0; ni < 4; ++ni)
            bfr[ni] = *(const bf16x8*)&ldsB[rd][wn * 64 + ni * 16 + frow][oK1];

        __builtin_amdgcn_s_setprio(1);
#pragma unroll
        for (int mi = 0; mi < 8; ++mi)
#pragma unroll
            for (int ni = 0; ni < 4; ++ni)
                acc[mi][ni] = MFMA16(af[mi], bfr[ni], acc[mi][ni]);
        __builtin_amdgcn_s_setprio(0);

        // publish B(t+1)
        if (m1) { CVTW(nB, 0, st0); CVTW(nB, 1, st1); }

        // one seal per K-tile: writes drained, reads consumed, buffers swap
        TILE_SEAL;
    }

    // epilogue: acc layout col=lane&15, row=(lane>>4)*4+r (m89-verified)
#pragma unroll
    for (int ni = 0; ni < 4; ++ni) {
        const int gc = tn * BN + wn * 64 + ni * 16 + frow;
        const float bv = Bias[bidx * NDIM + gc];
#pragma unroll
        for (int mi = 0; mi < 8; ++mi) {
            const int gr0 = tm * BM + wm * 128 + mi * 16 + (lane >> 4) * 4;
            float* po = Out + ((size_t)bidx * MDIM + gr0) * NDIM + gc;
#pragma unroll
            for (int r = 0; r < 4; ++r)
                po[(size_t)r * NDIM] = acc[mi][ni][r] + bv;
        }
    }
}

extern "C" void kernel_launch(void* const* d_in, const int* in_sizes, int n_in,
                              void* d_out, int out_size, void* d_ws, size_t ws_size,
                              hipStream_t stream) {
    const float* X  = (const float*)d_in[0];
    const float* W  = (const float*)d_in[1];
    const float* Bs = (const float*)d_in[2];
    float* Out = (float*)d_out;

    grouped_fc_kernel<<<dim3(512), dim3(512), 0, stream>>>(X, W, Bs, Out);
}